// Round 21
// baseline (46.530 us; speedup 1.0000x reference)
//
#include <hip/hip_runtime.h>
#include <math.h>

// Sizes fixed by the reference.
#define BSZ  16
#define DIM  1024
#define DPB  32        // d-channels per tile -> 128B FULL-LINE global granule
#define THREADS 1024   // 16 waves; ALL compute (32 half-waves = 32 images)
#define SSTRIDE 33     // LDS float-stride per s-cell: 33*31=1023==-1 (mod 32),
                       // banks (-i+dd+ts)%32 -> all 32 banks per half-wave
#define BUFF 34048     // floats: max idx 1023*31+31+33*67=33955, padded
#define LDSB (BUFF * 4)   // 136192 B -> 1 block/CU

__device__ __forceinline__ float sigmoidf_(float v) {
    return __builtin_amdgcn_rcpf(1.0f + __expf(-v));
}

// Barrier without __syncthreads()'s implicit vmcnt(0) drain.
__device__ __forceinline__ void soft_barrier() {
    asm volatile("s_waitcnt lgkmcnt(0)" ::: "memory");
    __builtin_amdgcn_s_barrier();
    asm volatile("" ::: "memory");
}

extern __shared__ float xs[];

// 2D SSM run as the recurrence directly on x (== causal conv with the impulse
// response == reference FFT path, by linearity/shift-invariance/causality).
//
// R21 — GRANULE PROBE. Six scheduling theories all null (38-45us). The
// fillBuffer comparison (6.7 TB/s, contiguous 1KB/instr) vs ours (3.4 TB/s,
// 16 scattered 64B segments/instr at DPB=16) points at per-request
// granularity. DPB=32 makes every stage/drain instruction cover 8 x 128B
// FULL L2 LINES (tile = 132KB LDS -> single buffer, serial
// stage|compute|drain, 1 block/CU, grid 512 = 2 sequential rounds).
// If granule is the limiter: ~32us. If not: ~48us (serialization cost)
// and the R14 plateau is the pattern roofline.
__global__ __launch_bounds__(THREADS, 1) void ssm2d_kernel(
    const float* __restrict__ x,
    const float* __restrict__ A1, const float* __restrict__ A2,
    const float* __restrict__ B1, const float* __restrict__ B2,
    const float* __restrict__ C1, const float* __restrict__ C2,
    const float* __restrict__ omega,
    float* __restrict__ out)
{
    const int lx   = blockIdx.x;           // 0..511
    const int dgrp = lx & 31;              // 0..31
    const int b    = lx >> 5;              // 0..15
    const int d0   = dgrp * DPB;
    const int t    = threadIdx.x;

    const int lane = t & 63;
    const int wv   = t >> 6;               // wave 0..15
    const int i    = lane & 31;            // row owned by this lane
    const int dd   = 2 * wv + (lane >> 5); // image (d-index) 0..31
    const int d    = d0 + dd;

    // ---- per-lane coefficients (all waves compute) ----
    const float2 fA1 = *reinterpret_cast<const float2*>(A1 + 2 * d);
    const float2 fA2 = *reinterpret_cast<const float2*>(A2 + 2 * d);
    const float2 fB1 = *reinterpret_cast<const float2*>(B1 + 2 * d);
    const float2 fB2 = *reinterpret_cast<const float2*>(B2 + 2 * d);
    const float2 fC1 = *reinterpret_cast<const float2*>(C1 + 2 * d);
    const float2 fC2 = *reinterpret_cast<const float2*>(C2 + 2 * d);
    const float  om  = omega[d];

    const float a1c0 = sigmoidf_(fA1.x) * 0.5f, a1c1 = sigmoidf_(fA1.y) * 0.5f;
    const float a2c0 = sigmoidf_(fA2.x) * 0.5f, a2c1 = sigmoidf_(fA2.y) * 0.5f;
    const float b1c0 = sigmoidf_(fB1.x) * 0.5f, b1c1 = sigmoidf_(fB1.y) * 0.5f;
    const float b2c0 = sigmoidf_(fB2.x) * 0.5f, b2c1 = sigmoidf_(fB2.y) * 0.5f;
    const float sc   = 0.70710678118654752f;
    const float c1s0 = fC1.x * sc, c1s1 = fC1.y * sc;
    const float c2s0 = fC2.x * sc, c2s1 = fC2.y * sc;
    const float a1z0 = (i == 0) ? 0.f : a1c0, a1z1 = (i == 0) ? 0.f : a1c1;
    const float a2z0 = (i == 0) ? 0.f : a2c0, a2z1 = (i == 0) ? 0.f : a2c1;

    // ---- stage/drain mapping: thread covers (srow = t>>3 + 128k, qq=(t&7)*4)
    // per wave-instruction: 8 s-rows x 128B CONTIGUOUS (full L2 lines).
    const int  srow0 = t >> 3;             // 0..127
    const int  qq    = (t & 7) * 4;        // 0..28
    const size_t gb  = (size_t)srow0 * (BSZ * DIM) + (size_t)b * DIM + d0 + qq;

    // ---- stage tile: 8 float4 loads -> LDS ----
    {
        float4 P[8];
        #pragma unroll
        for (int k2 = 0; k2 < 8; ++k2)
            P[k2] = *reinterpret_cast<const float4*>(
                x + gb + (size_t)k2 * (128 * BSZ * DIM));
        #pragma unroll
        for (int k2 = 0; k2 < 8; ++k2) {
            float* p = xs + SSTRIDE * (srow0 + 128 * k2) + qq;
            p[0] = P[k2].x; p[1] = P[k2].y; p[2] = P[k2].z; p[3] = P[k2].w;
        }
    }
    soft_barrier();

    // ---- compute: anti-diagonal recurrence, addr = 1023*i + dd + 33*ts ----
    float* rp = xs + 1023 * i + dd;

#define SBODY(XV_EXPR)                                                       \
        const float xv = (XV_EXPR);                                          \
        const float t10 = b1c0 * xv, t11 = b1c1 * xv;                        \
        const float hn0 = fmaf(a1c0, h0, fmaf(a2c0, v0, t10));               \
        const float hn1 = fmaf(a1c1, h1, fmaf(a2c1, v1, t11));               \
        float vn0 = b2c0 * xv, vn1 = b2c1 * xv;                              \
        asm("s_nop 1\n\t"                                                    \
            "v_fmac_f32_dpp %0, %2, %6 wave_shr:1 row_mask:0xf bank_mask:0xf bound_ctrl:0\n\t" \
            "v_fmac_f32_dpp %1, %3, %7 wave_shr:1 row_mask:0xf bank_mask:0xf bound_ctrl:0\n\t" \
            "v_fmac_f32_dpp %0, %4, %8 wave_shr:1 row_mask:0xf bank_mask:0xf bound_ctrl:0\n\t" \
            "v_fmac_f32_dpp %1, %5, %9 wave_shr:1 row_mask:0xf bank_mask:0xf bound_ctrl:0"     \
            : "+v"(vn0), "+v"(vn1)                                           \
            : "v"(h0), "v"(h1), "v"(v0), "v"(v1),                            \
              "v"(a2z0), "v"(a2z1), "v"(a1z0), "v"(a1z1));                   \
        float y = hn0 * c1s0;                                                \
        y = fmaf(hn1, c1s1, y);                                              \
        y = fmaf(vn0, c2s0, y);                                              \
        y = fmaf(vn1, c2s1, y);                                              \
        const float z = fmaf(xv, om, y);                                     \
        const float o = z * sigmoidf_(z);

#define SSTEP_PRE(TS, XQ) do {                                               \
        const bool val = (i <= (TS));                                        \
        SBODY(val ? (XQ) : 0.f)                                              \
        if (val) rp[SSTRIDE * (TS)] = o;                                     \
        h0 = hn0; h1 = hn1; v0 = vn0; v1 = vn1; } while (0)

#define SSTEP_POST(TS, XQ) do { SBODY(XQ)                                    \
        if (i >= (TS) - 31) rp[SSTRIDE * (TS)] = o;                          \
        h0 = hn0; h1 = hn1; v0 = vn0; v1 = vn1; } while (0)

    {
        float h0 = 0.f, h1 = 0.f, v0 = 0.f, v1 = 0.f;
        float xq0 = rp[0 * SSTRIDE];
        float xq1 = rp[1 * SSTRIDE];
        float xq2 = rp[2 * SSTRIDE];
        #pragma unroll
        for (int ts = 0; ts < 30; ts += 3) {
            SSTEP_PRE(ts + 0, xq0); xq0 = rp[SSTRIDE * (ts + 3)];
            SSTEP_PRE(ts + 1, xq1); xq1 = rp[SSTRIDE * (ts + 4)];
            SSTEP_PRE(ts + 2, xq2); xq2 = rp[SSTRIDE * (ts + 5)];
        }
        SSTEP_PRE(30, xq0); xq0 = rp[SSTRIDE * 33];
        #pragma unroll
        for (int ts = 31; ts < 61; ts += 3) {
            SSTEP_POST(ts + 0, xq1); xq1 = rp[SSTRIDE * (ts + 3)];
            SSTEP_POST(ts + 1, xq2); xq2 = rp[SSTRIDE * (ts + 4)];
            SSTEP_POST(ts + 2, xq0); xq0 = rp[SSTRIDE * (ts + 5)];
        }
        SSTEP_POST(61, xq1);
        SSTEP_POST(62, xq2);
    }
    soft_barrier();

    // ---- drain tile: LDS -> 8 float4 stores (full-line granule) ----
    {
        #pragma unroll
        for (int k2 = 0; k2 < 8; ++k2) {
            const float* p = xs + SSTRIDE * (srow0 + 128 * k2) + qq;
            float4 v; v.x = p[0]; v.y = p[1]; v.z = p[2]; v.w = p[3];
            *reinterpret_cast<float4*>(
                out + gb + (size_t)k2 * (128 * BSZ * DIM)) = v;
        }
    }
}

extern "C" void kernel_launch(void* const* d_in, const int* in_sizes, int n_in,
                              void* d_out, int out_size, void* d_ws, size_t ws_size,
                              hipStream_t stream) {
    const float* x     = (const float*)d_in[0];
    const float* A1    = (const float*)d_in[1];
    const float* A2    = (const float*)d_in[2];
    const float* B1    = (const float*)d_in[3];
    const float* B2    = (const float*)d_in[4];
    const float* C1    = (const float*)d_in[5];
    const float* C2    = (const float*)d_in[6];
    const float* omega = (const float*)d_in[7];
    float* out = (float*)d_out;

    (void)hipFuncSetAttribute(reinterpret_cast<const void*>(ssm2d_kernel),
                              hipFuncAttributeMaxDynamicSharedMemorySize, LDSB);

    dim3 grid(512);                 // 32 d-groups x 16 b; 1 tile/block
    dim3 block(THREADS);
    hipLaunchKernelGGL(ssm2d_kernel, grid, block, LDSB, stream,
                       x, A1, A2, B1, B2, C1, C2, omega, out);
}